// Round 8
// baseline (1540.555 us; speedup 1.0000x reference)
//
#include <hip/hip_runtime.h>
#include <math.h>

#define N_NODES 50000
#define N_EDGES 400000
#define C 32
#define NB 8
#define HID 64
#define NL 2
#define NG 64
#define RMAXF 5.0f
#define EPSF 1e-5f
#define NBLK_N ((N_NODES + 255) / 256)   // 196

__device__ __forceinline__ float silu_f(float x) { return x / (1.0f + __expf(-x)); }
__device__ __forceinline__ float sigmoid_f(float x) { return 1.0f / (1.0f + __expf(-x)); }
__device__ __forceinline__ void atomAddF(float* p, float val) {
  __hip_atomic_fetch_add(p, val, __ATOMIC_RELAXED, __HIP_MEMORY_SCOPE_AGENT);
}
__device__ __forceinline__ void atomAddD(double* p, double val) {
  __hip_atomic_fetch_add(p, val, __ATOMIC_RELAXED, __HIP_MEMORY_SCOPE_AGENT);
}
__device__ __forceinline__ unsigned bf16_rne(float f) {
  unsigned u = __float_as_uint(f);
  return (u + 0x7FFFu + ((u >> 16) & 1u)) >> 16;
}
__device__ __forceinline__ unsigned pack2(float lo, float hi) {
  return bf16_rne(lo) | (bf16_rne(hi) << 16);
}
__device__ __forceinline__ float unpack_bf(unsigned u, int hi) {
  unsigned h = hi ? (u & 0xFFFF0000u) : (u << 16);
  return __uint_as_float(h);
}

// ---------------- edge geometry: basis (E,8) + unit dir Y1 (E,3) ----------------
__global__ __launch_bounds__(256) void k_edge_geom(
    const float* __restrict__ pos, const int* __restrict__ ei,
    const float* __restrict__ freqs,
    float* __restrict__ basis, float* __restrict__ Y1)
{
  int e = blockIdx.x * 256 + threadIdx.x;
  if (e >= N_EDGES) return;
  int s = ei[e], d = ei[N_EDGES + e];
  float vx = pos[d*3+0] - pos[s*3+0];
  float vy = pos[d*3+1] - pos[s*3+1];
  float vz = pos[d*3+2] - pos[s*3+2];
  float dist = sqrtf(vx*vx + vy*vy + vz*vz);
  float invd = 1.0f / fmaxf(dist, 1e-9f);
  Y1[e*3+0] = vx*invd; Y1[e*3+1] = vy*invd; Y1[e*3+2] = vz*invd;
  float x = fminf(fmaxf(dist * (1.0f/RMAXF), 0.0f), 1.0f);
  float x2 = x*x, x3 = x2*x;
  float cut = 1.0f - x3 * (10.0f - 15.0f*x + 6.0f*x2);
  if (dist > RMAXF) cut = 0.0f;
  float rinv = cut / fmaxf(dist, 1e-6f);
  #pragma unroll
  for (int k = 0; k < NB; k++)
    basis[e*NB + k] = sinf(freqs[k] * dist) * rinv;
}

// ---------------- node init ----------------
__global__ __launch_bounds__(256) void k_node_init(
    const int* __restrict__ species, const float* __restrict__ emb, float* __restrict__ s)
{
  int i = blockIdx.x * 256 + threadIdx.x;
  if (i >= N_NODES * C) return;
  int n = i >> 5, c = i & 31;
  s[i] = emb[species[n]*C + c];
}

// ---------------- CSR build ----------------
__global__ __launch_bounds__(256) void k_hist(const int* __restrict__ ei, int* __restrict__ counts)
{
  int e = blockIdx.x * 256 + threadIdx.x;
  if (e >= N_EDGES) return;
  atomicAdd(&counts[ei[N_EDGES + e]], 1);
}

__global__ __launch_bounds__(256) void k_scanA(const int* __restrict__ counts, int* __restrict__ bsum)
{
  __shared__ int sh[256];
  int i = blockIdx.x * 256 + threadIdx.x;
  int x = (i < N_NODES) ? counts[i] : 0;
  sh[threadIdx.x] = x;
  __syncthreads();
  for (int off = 128; off > 0; off >>= 1) {
    if (threadIdx.x < off) sh[threadIdx.x] += sh[threadIdx.x + off];
    __syncthreads();
  }
  if (threadIdx.x == 0) bsum[blockIdx.x] = sh[0];
}

__global__ void k_scanB(int* __restrict__ bsum)
{
  if (threadIdx.x == 0) {
    int acc = 0;
    for (int b = 0; b < NBLK_N; b++) { int t = bsum[b]; bsum[b] = acc; acc += t; }
  }
}

__global__ __launch_bounds__(256) void k_scanC(const int* __restrict__ counts,
                                               const int* __restrict__ bsum,
                                               int* __restrict__ row_start)
{
  __shared__ int sh[256];
  int i = blockIdx.x * 256 + threadIdx.x;
  int x = (i < N_NODES) ? counts[i] : 0;
  sh[threadIdx.x] = x;
  __syncthreads();
  for (int off = 1; off < 256; off <<= 1) {
    int y = (threadIdx.x >= off) ? sh[threadIdx.x - off] : 0;
    __syncthreads();
    sh[threadIdx.x] += y;
    __syncthreads();
  }
  if (i < N_NODES) row_start[i] = bsum[blockIdx.x] + sh[threadIdx.x] - x; // exclusive
}

// scatter: build perm/srcs, pre-gather Y1 AND basis into sorted order
__global__ __launch_bounds__(256) void k_scatter(const int* __restrict__ ei,
                                                 const int* __restrict__ row_start,
                                                 int* __restrict__ cursor,
                                                 const float* __restrict__ Y1,
                                                 const float* __restrict__ basis,
                                                 int* __restrict__ perm,
                                                 int* __restrict__ srcs,
                                                 float* __restrict__ Y1s,
                                                 float* __restrict__ basis_s)
{
  int e = blockIdx.x * 256 + threadIdx.x;
  if (e >= N_EDGES) return;
  int d = ei[N_EDGES + e];
  int p = row_start[d] + atomicAdd(&cursor[d], 1);
  perm[p] = e;
  srcs[p] = ei[e];
  Y1s[p*3+0] = Y1[e*3+0];
  Y1s[p*3+1] = Y1[e*3+1];
  Y1s[p*3+2] = Y1[e*3+2];
  *(float4*)(basis_s + (size_t)p*NB)     = *(const float4*)(basis + (size_t)e*NB);
  *(float4*)(basis_s + (size_t)p*NB + 4) = *(const float4*)(basis + (size_t)e*NB + 4);
}

// ---------------- fused radial MLP, register-pressure-safe ----------------
// Block = 64 edges x 4 waves. Wave q: phase1 computes h2[q*16..q*16+16) (live ~30
// regs; h1 stream recomputed per wave, +17% cheap FMAs), silu+bf16-pack into LDS
// (stride 33 dwords -> conflict-free); barrier; phase2 computes outputs
// [q*32..q*32+32) in two a[16] passes reading h2 from LDS (live ~30 regs).
// q-per-wave keeps every weight index wave-uniform -> SGPR operands. No scratch.
// Stores: coalesced plane layout w[d][p] (r7's fix).
__global__ __launch_bounds__(256) void k_edge_mlp(
    const float* __restrict__ basis_s,
    const float* __restrict__ rW1, const float* __restrict__ rb1,
    const float* __restrict__ rW2, const float* __restrict__ rb2,
    const float* __restrict__ rW3, const float* __restrict__ rb3,
    unsigned* __restrict__ wout)
{
  __shared__ unsigned h2lds[64 * 33];          // 64 edges x (32 data + 1 pad) dwords
  int lane = threadIdx.x & 63;
  int q    = threadIdx.x >> 6;                 // 0..3, constant per wave
  int p    = blockIdx.x * 64 + lane;           // sorted edge index (E % 64 == 0)

  const float4 b0 = *(const float4*)(basis_s + (size_t)p*NB);
  const float4 b1 = *(const float4*)(basis_s + (size_t)p*NB + 4);
  float bas[NB] = {b0.x, b0.y, b0.z, b0.w, b1.x, b1.y, b1.z, b1.w};

  // ---- phase 1: h2 quarter [q*16, q*16+16) ----
  float hq[16];
  {
    const float* rb = rb2 + q*16;
    #pragma unroll
    for (int j = 0; j < 16; j++) hq[j] = rb[j];
  }
  #pragma unroll 2
  for (int k = 0; k < HID; k++) {
    float t = rb1[k];
    #pragma unroll
    for (int b = 0; b < NB; b++) t = fmaf(bas[b], rW1[b*HID + k], t);
    float h1k = silu_f(t);
    const float* r = rW2 + k*HID + q*16;
    #pragma unroll
    for (int j = 0; j < 16; j++) hq[j] = fmaf(h1k, r[j], hq[j]);
  }
  {
    unsigned* row = h2lds + lane*33 + q*8;
    #pragma unroll
    for (int j = 0; j < 8; j++)
      row[j] = pack2(silu_f(hq[2*j]), silu_f(hq[2*j+1]));
  }
  __syncthreads();

  // ---- phase 2: outputs [q*32, q*32+32), two passes of 16 ----
  const unsigned* row2 = h2lds + lane*33;
  #pragma unroll 1
  for (int pass = 0; pass < 2; pass++) {
    int obase = q*32 + pass*16;
    float a[16];
    {
      const float* rb = rb3 + obase;
      #pragma unroll
      for (int i = 0; i < 16; i++) a[i] = rb[i];
    }
    #pragma unroll 2
    for (int k2 = 0; k2 < 32; k2++) {          // dword index into h2 row
      unsigned hp = row2[k2];
      float h0 = unpack_bf(hp, 0);
      float h1 = unpack_bf(hp, 1);
      const float* r0 = rW3 + (2*k2)*4*C + obase;
      const float* r1 = r0 + 4*C;
      #pragma unroll
      for (int i = 0; i < 16; i++) a[i] = fmaf(h0, r0[i], a[i]);
      #pragma unroll
      for (int i = 0; i < 16; i++) a[i] = fmaf(h1, r1[i], a[i]);
    }
    int d0 = obase >> 1;
    #pragma unroll
    for (int i = 0; i < 8; i++)
      wout[(size_t)(d0 + i)*N_EDGES + p] = pack2(a[2*i], a[2*i+1]);
  }
}

// ---------------- aggregate + gate + self-interaction + BN stats ----------------
// 32 lanes per node (c = lane&31); grid covers exactly N_NODES*32 threads.
// w is in plane layout: dword d of edge p at w[d*N_EDGES + p].
__global__ __launch_bounds__(256) void k_agg_update(
    const unsigned* __restrict__ w, const float* __restrict__ Y1s,
    const int* __restrict__ srcs,
    const int* __restrict__ row_start, const int* __restrict__ counts,
    const float* __restrict__ s, const float* __restrict__ v,
    const float* __restrict__ Wss, const float* __restrict__ bss,
    const float* __restrict__ Wvv,
    float* __restrict__ s_new, float* __restrict__ v_new,
    double* __restrict__ bn_sums)
{
  __shared__ float lacc[3*C];
  int t = blockIdx.x * 256 + threadIdx.x;
  int n = t >> 5;
  int c = t & 31;
  if (threadIdx.x < 3*C) lacc[threadIdx.x] = 0.0f;
  __syncthreads();

  int ci = c >> 1, sel = c & 1;
  const unsigned* w1p = w + (size_t)ci * N_EDGES;
  const unsigned* w2p = w + (size_t)(16 + ci) * N_EDGES;
  const unsigned* w3p = w + (size_t)(32 + ci) * N_EDGES;
  const unsigned* w4p = w + (size_t)(48 + ci) * N_EDGES;

  float asf = 0.0f, asg = 0.0f, av0 = 0.0f, av1 = 0.0f, av2 = 0.0f;
  int beg = row_start[n], cnt = counts[n];
  for (int i = 0; i < cnt; i++) {
    int p = beg + i;
    float w1 = unpack_bf(w1p[p], sel);
    float w2 = unpack_bf(w2p[p], sel);
    float w3 = unpack_bf(w3p[p], sel);
    float w4 = unpack_bf(w4p[p], sel);
    int src = srcs[p];
    float y0 = Y1s[p*3+0], y1 = Y1s[p*3+1], y2 = Y1s[p*3+2];
    float xs = s[src*C + c];
    const float* vp = v + (size_t)(src*C + c)*3;
    float xv0 = vp[0], xv1 = vp[1], xv2 = vp[2];
    asf = fmaf(w1, xs, asf);
    asg = fmaf(w2, xv0*y0 + xv1*y1 + xv2*y2, asg);
    float w3xs = w3 * xs;
    av0 += fmaf(w3xs, y0, w4*xv0);
    av1 += fmaf(w3xs, y1, w4*xv1);
    av2 += fmaf(w3xs, y2, w4*xv2);
  }

  float sgv  = silu_f(asf);
  float gate = sigmoid_f(asg);
  float vg0 = gate*av0, vg1 = gate*av1, vg2 = gate*av2;

  float sn = bss[c];
  float vm0 = 0.0f, vm1 = 0.0f, vm2 = 0.0f;
  #pragma unroll
  for (int k = 0; k < C; k++) {
    float a  = __shfl(sgv, k, 32);
    sn = fmaf(a, Wss[k*C + c], sn);
    float wv = Wvv[k*C + c];
    vm0 = fmaf(__shfl(vg0, k, 32), wv, vm0);
    vm1 = fmaf(__shfl(vg1, k, 32), wv, vm1);
    vm2 = fmaf(__shfl(vg2, k, 32), wv, vm2);
  }

  s_new[n*C + c] = sn;
  float* vo = v_new + (size_t)(n*C + c)*3;
  vo[0] = vm0; vo[1] = vm1; vo[2] = vm2;

  float vn2 = vm0*vm0 + vm1*vm1 + vm2*vm2;
  atomicAdd(&lacc[c],       sn);
  atomicAdd(&lacc[C + c],   sn*sn);
  atomicAdd(&lacc[2*C + c], vn2);
  __syncthreads();
  if (threadIdx.x < 3*C) atomAddD(&bn_sums[threadIdx.x], (double)lacc[threadIdx.x]);
}

// ---------------- BN scales ----------------
__global__ void k_bn_scales(const double* __restrict__ bn_sums,
                            const float* __restrict__ gs, const float* __restrict__ gv,
                            float* __restrict__ scales)
{
  int m = threadIdx.x;
  if (m >= C) return;
  double S1 = bn_sums[m], S2 = bn_sums[C + m], VN = bn_sums[2*C + m];
  double mu  = S1 / (double)N_NODES;
  double var = S2 / (double)N_NODES - mu*mu;
  double vn2 = VN / (3.0 * (double)N_NODES);
  scales[m]       = (float)mu;
  scales[C + m]   = gs[m] / sqrtf((float)var + EPSF);
  scales[2*C + m] = gv[m] / sqrtf((float)vn2 + EPSF);
}

// ---------------- apply BN + residual ----------------
__global__ __launch_bounds__(256) void k_apply(
    const float* __restrict__ s_new, const float* __restrict__ v_new,
    const float* __restrict__ scales, const float* __restrict__ bn_bs,
    float* __restrict__ s, float* __restrict__ v)
{
  int i = blockIdx.x * 256 + threadIdx.x;
  if (i >= N_NODES * C) return;
  int c = i & 31;
  s[i] += (s_new[i] - scales[c]) * scales[C + c] + bn_bs[c];
  float vs = scales[2*C + c];
  v[(size_t)i*3+0] += v_new[(size_t)i*3+0] * vs;
  v[(size_t)i*3+1] += v_new[(size_t)i*3+1] * vs;
  v[(size_t)i*3+2] += v_new[(size_t)i*3+2] * vs;
}

// ---------------- readout ----------------
__global__ __launch_bounds__(256) void k_readout(
    const float* __restrict__ s, const int* __restrict__ species,
    const int* __restrict__ batch,
    const float* __restrict__ W_out, const float* __restrict__ b_out,
    const float* __restrict__ atom_ref, float* __restrict__ out)
{
  __shared__ float acc[NG];
  if (threadIdx.x < NG) acc[threadIdx.x] = 0.0f;
  __syncthreads();
  int n = blockIdx.x * 256 + threadIdx.x;
  if (n < N_NODES) {
    float e = b_out[0] + atom_ref[species[n]];
    #pragma unroll
    for (int c = 0; c < C; c++) e = fmaf(s[n*C + c], W_out[c], e);
    atomicAdd(&acc[batch[n]], e);
  }
  __syncthreads();
  if (threadIdx.x < NG) {
    float a = acc[threadIdx.x];
    if (a != 0.0f) atomAddF(&out[threadIdx.x], a);
  }
}

// ================= FALLBACK (atomic path, used only if ws too small) ==========
__global__ __launch_bounds__(256) void k_edge_msg_fb(
    const float* __restrict__ basis, const float* __restrict__ Y1,
    const int* __restrict__ ei,
    const float* __restrict__ s, const float* __restrict__ v,
    const float* __restrict__ rW1, const float* __restrict__ rb1,
    const float* __restrict__ rW2, const float* __restrict__ rb2,
    const float* __restrict__ rW3, const float* __restrict__ rb3,
    float* __restrict__ agg_sf, float* __restrict__ agg_sg, float* __restrict__ agg_v)
{
  int e = blockIdx.x * 256 + threadIdx.x;
  if (e >= N_EDGES) return;
  int src = ei[e], dst = ei[N_EDGES + e];
  const float4 b0 = *(const float4*)(basis + (size_t)e*NB);
  const float4 b1 = *(const float4*)(basis + (size_t)e*NB + 4);
  float bas[NB] = {b0.x, b0.y, b0.z, b0.w, b1.x, b1.y, b1.z, b1.w};
  float h2[HID];
  #pragma unroll
  for (int j = 0; j < HID; j++) h2[j] = rb2[j];
  #pragma unroll 2
  for (int k = 0; k < HID; k++) {
    float t = rb1[k];
    #pragma unroll
    for (int b = 0; b < NB; b++) t = fmaf(bas[b], rW1[b*HID + k], t);
    float h1k = silu_f(t);
    const float* r = rW2 + k*HID;
    #pragma unroll
    for (int j = 0; j < HID; j++) h2[j] = fmaf(h1k, r[j], h2[j]);
  }
  #pragma unroll
  for (int j = 0; j < HID; j++) h2[j] = silu_f(h2[j]);
  float y0 = Y1[e*3+0], y1 = Y1[e*3+1], y2 = Y1[e*3+2];
  #pragma unroll 1
  for (int cb = 0; cb < 16; cb++) {
    float a[8];
    #pragma unroll
    for (int ci = 0; ci < 8; ci++) a[ci] = rb3[cb*8 + ci];
    #pragma unroll
    for (int k = 0; k < HID; k++) {
      float h = h2[k];
      #pragma unroll
      for (int ci = 0; ci < 8; ci++) a[ci] = fmaf(h, rW3[k*4*C + cb*8 + ci], a[ci]);
    }
    #pragma unroll
    for (int ci = 0; ci < 8; ci++) {
      int o = cb*8 + ci;
      int path = o >> 5;
      int c = o & 31;
      float xs = s[src*C + c];
      const float* vp = v + (size_t)(src*C + c)*3;
      float xv0 = vp[0], xv1 = vp[1], xv2 = vp[2];
      if (path == 0) {
        atomAddF(&agg_sf[dst*C + c], a[ci] * xs);
      } else if (path == 1) {
        atomAddF(&agg_sg[dst*C + c], a[ci] * (xv0*y0 + xv1*y1 + xv2*y2));
      } else if (path == 2) {
        float w3xs = a[ci] * xs;
        float* ap = agg_v + (size_t)(dst*C + c)*3;
        atomAddF(ap+0, w3xs*y0); atomAddF(ap+1, w3xs*y1); atomAddF(ap+2, w3xs*y2);
      } else {
        float* ap = agg_v + (size_t)(dst*C + c)*3;
        atomAddF(ap+0, a[ci]*xv0); atomAddF(ap+1, a[ci]*xv1); atomAddF(ap+2, a[ci]*xv2);
      }
    }
  }
}

__global__ __launch_bounds__(256) void k_node_update_fb(
    const float* __restrict__ agg_sf, const float* __restrict__ agg_sg,
    const float* __restrict__ agg_v,
    const float* __restrict__ Wss, const float* __restrict__ bss,
    const float* __restrict__ Wvv,
    float* __restrict__ s_new, float* __restrict__ v_new,
    double* __restrict__ bn_sums)
{
  __shared__ float lacc[3*C];
  int t = blockIdx.x * 256 + threadIdx.x;
  int n = t >> 5;
  int c = t & 31;
  if (threadIdx.x < 3*C) lacc[threadIdx.x] = 0.0f;
  __syncthreads();
  float asf = agg_sf[n*C + c];
  float asg = agg_sg[n*C + c];
  const float* ap = agg_v + (size_t)(n*C + c)*3;
  float av0 = ap[0], av1 = ap[1], av2 = ap[2];
  float sgv = silu_f(asf);
  float gate = sigmoid_f(asg);
  float vg0 = gate*av0, vg1 = gate*av1, vg2 = gate*av2;
  float sn = bss[c];
  float vm0 = 0.0f, vm1 = 0.0f, vm2 = 0.0f;
  #pragma unroll
  for (int k = 0; k < C; k++) {
    float a  = __shfl(sgv, k, 32);
    sn = fmaf(a, Wss[k*C + c], sn);
    float wv = Wvv[k*C + c];
    vm0 = fmaf(__shfl(vg0, k, 32), wv, vm0);
    vm1 = fmaf(__shfl(vg1, k, 32), wv, vm1);
    vm2 = fmaf(__shfl(vg2, k, 32), wv, vm2);
  }
  s_new[n*C + c] = sn;
  float* vo = v_new + (size_t)(n*C + c)*3;
  vo[0] = vm0; vo[1] = vm1; vo[2] = vm2;
  float vn2 = vm0*vm0 + vm1*vm1 + vm2*vm2;
  atomicAdd(&lacc[c], sn);
  atomicAdd(&lacc[C + c], sn*sn);
  atomicAdd(&lacc[2*C + c], vn2);
  __syncthreads();
  if (threadIdx.x < 3*C) atomAddD(&bn_sums[threadIdx.x], (double)lacc[threadIdx.x]);
}

extern "C" void kernel_launch(void* const* d_in, const int* in_sizes, int n_in,
                              void* d_out, int out_size, void* d_ws, size_t ws_size,
                              hipStream_t stream)
{
  const int*   species  = (const int*)  d_in[0];
  const float* pos      = (const float*)d_in[1];
  const int*   ei       = (const int*)  d_in[2];
  const int*   batch    = (const int*)  d_in[3];
  const float* emb      = (const float*)d_in[4];
  const float* freqs    = (const float*)d_in[5];
  const float* rW1      = (const float*)d_in[6];
  const float* rb1      = (const float*)d_in[7];
  const float* rW2      = (const float*)d_in[8];
  const float* rb2      = (const float*)d_in[9];
  const float* rW3      = (const float*)d_in[10];
  const float* rb3      = (const float*)d_in[11];
  const float* Wss      = (const float*)d_in[12];
  const float* bss      = (const float*)d_in[13];
  const float* Wvv      = (const float*)d_in[14];
  const float* bn_gs    = (const float*)d_in[15];
  const float* bn_bs    = (const float*)d_in[16];
  const float* bn_gv    = (const float*)d_in[17];
  const float* W_out    = (const float*)d_in[18];
  const float* b_out    = (const float*)d_in[19];
  const float* atom_ref = (const float*)d_in[20];

  float* ws = (float*)d_ws;
  size_t off = 0;
  float* basis  = ws + off; off += (size_t)N_EDGES * NB;
  float* Y1     = ws + off; off += (size_t)N_EDGES * 3;
  float* s      = ws + off; off += (size_t)N_NODES * C;
  float* v      = ws + off; off += (size_t)N_NODES * C * 3;
  float* s_new  = ws + off; off += (size_t)N_NODES * C;
  float* v_new  = ws + off; off += (size_t)N_NODES * C * 3;
  double* bn_sums = (double*)(ws + off); off += 192;
  float* scales = ws + off; off += 96;

  // --- region A (sorted path) ---
  size_t ra = off;
  float* Y1s      = ws + ra;            ra += (size_t)N_EDGES * 3;
  float* basis_s  = ws + ra;            ra += (size_t)N_EDGES * NB;
  int*   perm     = (int*)(ws + ra);    ra += N_EDGES;
  int*   srcs     = (int*)(ws + ra);    ra += N_EDGES;
  int*   counts   = (int*)(ws + ra);    ra += N_NODES;
  int*   row_start= (int*)(ws + ra);    ra += N_NODES;
  int*   cursor   = (int*)(ws + ra);    ra += N_NODES;
  int*   bsum     = (int*)(ws + ra);    ra += 256;
  unsigned* wbuf  = (unsigned*)(ws + ra); ra += (size_t)N_EDGES * 64;
  size_t req_sorted = ra * 4;

  // --- region B (fallback atomic path, aliases region A) ---
  size_t rb = off;
  float* agg_sf = ws + rb; rb += (size_t)N_NODES * C;
  float* agg_sg = ws + rb; rb += (size_t)N_NODES * C;
  float* agg_v  = ws + rb; rb += (size_t)N_NODES * C * 3;

  dim3 b256(256);
  const int gE  = (N_EDGES + 255) / 256;
  const int gNC = (N_NODES * C + 255) / 256;
  const int gN  = (N_NODES + 255) / 256;

  hipMemsetAsync(v, 0, (size_t)N_NODES * C * 3 * sizeof(float), stream);
  k_edge_geom<<<gE, b256, 0, stream>>>(pos, ei, freqs, basis, Y1);
  k_node_init<<<gNC, b256, 0, stream>>>(species, emb, s);

  if (ws_size >= req_sorted) {
    hipMemsetAsync(counts, 0, N_NODES * sizeof(int), stream);
    hipMemsetAsync(cursor, 0, N_NODES * sizeof(int), stream);
    k_hist<<<gE, b256, 0, stream>>>(ei, counts);
    k_scanA<<<NBLK_N, b256, 0, stream>>>(counts, bsum);
    k_scanB<<<1, 64, 0, stream>>>(bsum);
    k_scanC<<<NBLK_N, b256, 0, stream>>>(counts, bsum, row_start);
    k_scatter<<<gE, b256, 0, stream>>>(ei, row_start, cursor, Y1, basis,
                                       perm, srcs, Y1s, basis_s);

    for (int l = 0; l < NL; l++) {
      hipMemsetAsync(bn_sums, 0, 96 * sizeof(double), stream);
      k_edge_mlp<<<N_EDGES/64, b256, 0, stream>>>(basis_s,
          rW1 + l*NB*HID, rb1 + l*HID, rW2 + l*HID*HID, rb2 + l*HID,
          rW3 + l*HID*4*C, rb3 + l*4*C, wbuf);
      k_agg_update<<<(N_NODES*C)/256, b256, 0, stream>>>(wbuf, Y1s, srcs,
          row_start, counts, s, v, Wss + l*C*C, bss + l*C, Wvv + l*C*C,
          s_new, v_new, bn_sums);
      k_bn_scales<<<1, 64, 0, stream>>>(bn_sums, bn_gs + l*C, bn_gv + l*C, scales);
      k_apply<<<gNC, b256, 0, stream>>>(s_new, v_new, scales, bn_bs + l*C, s, v);
    }
  } else {
    for (int l = 0; l < NL; l++) {
      hipMemsetAsync(agg_sf, 0, (size_t)N_NODES * 5 * C * sizeof(float), stream);
      hipMemsetAsync(bn_sums, 0, 96 * sizeof(double), stream);
      k_edge_msg_fb<<<gE, b256, 0, stream>>>(basis, Y1, ei, s, v,
          rW1 + l*NB*HID, rb1 + l*HID, rW2 + l*HID*HID, rb2 + l*HID,
          rW3 + l*HID*4*C, rb3 + l*4*C, agg_sf, agg_sg, agg_v);
      k_node_update_fb<<<(N_NODES*C)/256, b256, 0, stream>>>(agg_sf, agg_sg, agg_v,
          Wss + l*C*C, bss + l*C, Wvv + l*C*C, s_new, v_new, bn_sums);
      k_bn_scales<<<1, 64, 0, stream>>>(bn_sums, bn_gs + l*C, bn_gv + l*C, scales);
      k_apply<<<gNC, b256, 0, stream>>>(s_new, v_new, scales, bn_bs + l*C, s, v);
    }
  }

  hipMemsetAsync(d_out, 0, NG * sizeof(float), stream);
  k_readout<<<gN, b256, 0, stream>>>(s, species, batch, W_out, b_out, atom_ref, (float*)d_out);
}

// Round 9
// 505.299 us; speedup vs baseline: 3.0488x; 3.0488x over previous
//
#include <hip/hip_runtime.h>
#include <math.h>

#define N_NODES 50000
#define N_EDGES 400000
#define C 32
#define NB 8
#define HID 64
#define NL 2
#define NG 64
#define RMAXF 5.0f
#define EPSF 1e-5f
#define TBL 4096
#define NBLK_N ((N_NODES + 255) / 256)   // 196

__device__ __forceinline__ float silu_f(float x) { return x / (1.0f + __expf(-x)); }
__device__ __forceinline__ float sigmoid_f(float x) { return 1.0f / (1.0f + __expf(-x)); }
__device__ __forceinline__ void atomAddF(float* p, float val) {
  __hip_atomic_fetch_add(p, val, __ATOMIC_RELAXED, __HIP_MEMORY_SCOPE_AGENT);
}
__device__ __forceinline__ void atomAddD(double* p, double val) {
  __hip_atomic_fetch_add(p, val, __ATOMIC_RELAXED, __HIP_MEMORY_SCOPE_AGENT);
}

// ---------------- edge geometry: basis (fb only), dist (E), unit dir Y1 (E,3) -----
__global__ __launch_bounds__(256) void k_edge_geom(
    const float* __restrict__ pos, const int* __restrict__ ei,
    const float* __restrict__ freqs,
    float* __restrict__ basis, float* __restrict__ Y1, float* __restrict__ distb)
{
  int e = blockIdx.x * 256 + threadIdx.x;
  if (e >= N_EDGES) return;
  int s = ei[e], d = ei[N_EDGES + e];
  float vx = pos[d*3+0] - pos[s*3+0];
  float vy = pos[d*3+1] - pos[s*3+1];
  float vz = pos[d*3+2] - pos[s*3+2];
  float dist = sqrtf(vx*vx + vy*vy + vz*vz);
  float invd = 1.0f / fmaxf(dist, 1e-9f);
  Y1[e*3+0] = vx*invd; Y1[e*3+1] = vy*invd; Y1[e*3+2] = vz*invd;
  distb[e] = dist;
  float x = fminf(fmaxf(dist * (1.0f/RMAXF), 0.0f), 1.0f);
  float x2 = x*x, x3 = x2*x;
  float cut = 1.0f - x3 * (10.0f - 15.0f*x + 6.0f*x2);
  if (dist > RMAXF) cut = 0.0f;
  float rinv = cut / fmaxf(dist, 1e-6f);
  #pragma unroll
  for (int k = 0; k < NB; k++)
    basis[e*NB + k] = sinf(freqs[k] * dist) * rinv;
}

// ---------------- node init ----------------
__global__ __launch_bounds__(256) void k_node_init(
    const int* __restrict__ species, const float* __restrict__ emb, float* __restrict__ s)
{
  int i = blockIdx.x * 256 + threadIdx.x;
  if (i >= N_NODES * C) return;
  int n = i >> 5, c = i & 31;
  s[i] = emb[species[n]*C + c];
}

// ---------------- CSR build ----------------
__global__ __launch_bounds__(256) void k_hist(const int* __restrict__ ei, int* __restrict__ counts)
{
  int e = blockIdx.x * 256 + threadIdx.x;
  if (e >= N_EDGES) return;
  atomicAdd(&counts[ei[N_EDGES + e]], 1);
}

__global__ __launch_bounds__(256) void k_scanA(const int* __restrict__ counts, int* __restrict__ bsum)
{
  __shared__ int sh[256];
  int i = blockIdx.x * 256 + threadIdx.x;
  int x = (i < N_NODES) ? counts[i] : 0;
  sh[threadIdx.x] = x;
  __syncthreads();
  for (int off = 128; off > 0; off >>= 1) {
    if (threadIdx.x < off) sh[threadIdx.x] += sh[threadIdx.x + off];
    __syncthreads();
  }
  if (threadIdx.x == 0) bsum[blockIdx.x] = sh[0];
}

__global__ void k_scanB(int* __restrict__ bsum)
{
  if (threadIdx.x == 0) {
    int acc = 0;
    for (int b = 0; b < NBLK_N; b++) { int t = bsum[b]; bsum[b] = acc; acc += t; }
  }
}

__global__ __launch_bounds__(256) void k_scanC(const int* __restrict__ counts,
                                               const int* __restrict__ bsum,
                                               int* __restrict__ row_start)
{
  __shared__ int sh[256];
  int i = blockIdx.x * 256 + threadIdx.x;
  int x = (i < N_NODES) ? counts[i] : 0;
  sh[threadIdx.x] = x;
  __syncthreads();
  for (int off = 1; off < 256; off <<= 1) {
    int y = (threadIdx.x >= off) ? sh[threadIdx.x - off] : 0;
    __syncthreads();
    sh[threadIdx.x] += y;
    __syncthreads();
  }
  if (i < N_NODES) row_start[i] = bsum[blockIdx.x] + sh[threadIdx.x] - x; // exclusive
}

// scatter: pre-gather dist, Y1, src into dst-sorted order
__global__ __launch_bounds__(256) void k_scatter(const int* __restrict__ ei,
                                                 const int* __restrict__ row_start,
                                                 int* __restrict__ cursor,
                                                 const float* __restrict__ Y1,
                                                 const float* __restrict__ distb,
                                                 int* __restrict__ srcs,
                                                 float* __restrict__ Y1s,
                                                 float* __restrict__ dist_s)
{
  int e = blockIdx.x * 256 + threadIdx.x;
  if (e >= N_EDGES) return;
  int d = ei[N_EDGES + e];
  int p = row_start[d] + atomicAdd(&cursor[d], 1);
  srcs[p] = ei[e];
  dist_s[p] = distb[e];
  Y1s[p*3+0] = Y1[e*3+0];
  Y1s[p*3+1] = Y1[e*3+1];
  Y1s[p*3+2] = Y1[e*3+2];
}

// ---------------- radial-MLP tabulation ----------------
// w(dist) is a smooth 1-D function -> tabulate at TBL samples over [0, RMAX].
// Beyond RMAX the cutoff zeroes the basis, so w is exactly the last row (d=5, cut=0).
// Stage 1: h2 rows for [NL][TBL] samples (8192 MLP evals, trivial vs 400K).
__global__ __launch_bounds__(256) void k_table_h(
    const float* __restrict__ freqs,
    const float* __restrict__ rW1, const float* __restrict__ rb1,
    const float* __restrict__ rW2, const float* __restrict__ rb2,
    float* __restrict__ h2tab)                 // [NL*TBL*HID]
{
  int idx = blockIdx.x * 256 + threadIdx.x;    // [NL*TBL]
  if (idx >= NL * TBL) return;
  int l = idx / TBL, i = idx - l * TBL;
  float d = (float)i * (RMAXF / (float)(TBL - 1));
  float x = fminf(fmaxf(d * (1.0f/RMAXF), 0.0f), 1.0f);
  float x2 = x*x, x3 = x2*x;
  float cut = 1.0f - x3 * (10.0f - 15.0f*x + 6.0f*x2);
  float rinv = cut / fmaxf(d, 1e-6f);
  float bas[NB];
  #pragma unroll
  for (int k = 0; k < NB; k++) bas[k] = sinf(freqs[k] * d) * rinv;

  const float* W1 = rW1 + l*NB*HID;
  const float* B1 = rb1 + l*HID;
  const float* W2 = rW2 + l*HID*HID;
  const float* B2 = rb2 + l*HID;

  float h2[HID];
  #pragma unroll
  for (int j = 0; j < HID; j++) h2[j] = B2[j];
  #pragma unroll 2
  for (int k = 0; k < HID; k++) {
    float t = B1[k];
    #pragma unroll
    for (int b = 0; b < NB; b++) t = fmaf(bas[b], W1[b*HID + k], t);
    float h1k = silu_f(t);
    const float* r = W2 + k*HID;
    #pragma unroll
    for (int j = 0; j < HID; j++) h2[j] = fmaf(h1k, r[j], h2[j]);
  }
  float* out = h2tab + (size_t)idx * HID;
  #pragma unroll
  for (int j = 0; j < HID; j++) out[j] = silu_f(h2[j]);
}

// Stage 2: layer-3 (64->128) per (sample, 8-output chunk); 131K threads.
__global__ __launch_bounds__(256) void k_table_w(
    const float* __restrict__ h2tab,
    const float* __restrict__ rW3, const float* __restrict__ rb3,
    float* __restrict__ wtab)                  // [NL*TBL*128]
{
  int idx = blockIdx.x * 256 + threadIdx.x;    // [NL*TBL*16]
  if (idx >= NL * TBL * 16) return;
  int chunk = idx & 15;
  int row   = idx >> 4;                        // l*TBL + i
  int l     = row / TBL;
  const float* h2 = h2tab + (size_t)row * HID;
  const float* W3 = rW3 + l*HID*4*C + chunk*8;
  const float* B3 = rb3 + l*4*C + chunk*8;
  float a[8];
  #pragma unroll
  for (int ci = 0; ci < 8; ci++) a[ci] = B3[ci];
  #pragma unroll 4
  for (int k = 0; k < HID; k++) {
    float h = h2[k];
    #pragma unroll
    for (int ci = 0; ci < 8; ci++) a[ci] = fmaf(h, W3[k*4*C + ci], a[ci]);
  }
  float* out = wtab + (size_t)row * 128 + chunk*8;
  #pragma unroll
  for (int ci = 0; ci < 8; ci++) out[ci] = a[ci];
}

// ---------------- aggregate (w via table lerp) + gate + self-int + BN stats -------
// 32 lanes per node (c = lane&31). Table rows are 128 floats; per path the 32
// lanes read 128B contiguous (coalesced), table is L2-resident (2MB/layer).
__global__ __launch_bounds__(256) void k_agg_update(
    const float* __restrict__ tb,              // this layer's wtab [TBL][128]
    const float* __restrict__ dist_s, const float* __restrict__ Y1s,
    const int* __restrict__ srcs,
    const int* __restrict__ row_start, const int* __restrict__ counts,
    const float* __restrict__ s, const float* __restrict__ v,
    const float* __restrict__ Wss, const float* __restrict__ bss,
    const float* __restrict__ Wvv,
    float* __restrict__ s_new, float* __restrict__ v_new,
    double* __restrict__ bn_sums)
{
  __shared__ float lacc[3*C];
  int t = blockIdx.x * 256 + threadIdx.x;
  int n = t >> 5;
  int c = t & 31;
  if (threadIdx.x < 3*C) lacc[threadIdx.x] = 0.0f;
  __syncthreads();

  const float SCALE = (float)(TBL - 1) / RMAXF;
  float asf = 0.0f, asg = 0.0f, av0 = 0.0f, av1 = 0.0f, av2 = 0.0f;
  int beg = row_start[n], cnt = counts[n];
  for (int i = 0; i < cnt; i++) {
    int p = beg + i;
    float d  = dist_s[p];
    float ts = fminf(d, RMAXF) * SCALE;
    int   t0 = (int)ts;
    t0 = t0 > TBL - 2 ? TBL - 2 : t0;
    float fr = ts - (float)t0;
    const float* r0 = tb + (size_t)t0 * 128 + c;
    const float* r1 = r0 + 128;
    float w1 = fmaf(fr, r1[0]   - r0[0],   r0[0]);
    float w2 = fmaf(fr, r1[32]  - r0[32],  r0[32]);
    float w3 = fmaf(fr, r1[64]  - r0[64],  r0[64]);
    float w4 = fmaf(fr, r1[96]  - r0[96],  r0[96]);
    int src = srcs[p];
    float y0 = Y1s[p*3+0], y1 = Y1s[p*3+1], y2 = Y1s[p*3+2];
    float xs = s[src*C + c];
    const float* vp = v + (size_t)(src*C + c)*3;
    float xv0 = vp[0], xv1 = vp[1], xv2 = vp[2];
    asf = fmaf(w1, xs, asf);
    asg = fmaf(w2, xv0*y0 + xv1*y1 + xv2*y2, asg);
    float w3xs = w3 * xs;
    av0 += fmaf(w3xs, y0, w4*xv0);
    av1 += fmaf(w3xs, y1, w4*xv1);
    av2 += fmaf(w3xs, y2, w4*xv2);
  }

  float sgv  = silu_f(asf);
  float gate = sigmoid_f(asg);
  float vg0 = gate*av0, vg1 = gate*av1, vg2 = gate*av2;

  float sn = bss[c];
  float vm0 = 0.0f, vm1 = 0.0f, vm2 = 0.0f;
  #pragma unroll
  for (int k = 0; k < C; k++) {
    float a  = __shfl(sgv, k, 32);
    sn = fmaf(a, Wss[k*C + c], sn);
    float wv = Wvv[k*C + c];
    vm0 = fmaf(__shfl(vg0, k, 32), wv, vm0);
    vm1 = fmaf(__shfl(vg1, k, 32), wv, vm1);
    vm2 = fmaf(__shfl(vg2, k, 32), wv, vm2);
  }

  s_new[n*C + c] = sn;
  float* vo = v_new + (size_t)(n*C + c)*3;
  vo[0] = vm0; vo[1] = vm1; vo[2] = vm2;

  float vn2 = vm0*vm0 + vm1*vm1 + vm2*vm2;
  atomicAdd(&lacc[c],       sn);
  atomicAdd(&lacc[C + c],   sn*sn);
  atomicAdd(&lacc[2*C + c], vn2);
  __syncthreads();
  if (threadIdx.x < 3*C) atomAddD(&bn_sums[threadIdx.x], (double)lacc[threadIdx.x]);
}

// ---------------- BN scales ----------------
__global__ void k_bn_scales(const double* __restrict__ bn_sums,
                            const float* __restrict__ gs, const float* __restrict__ gv,
                            float* __restrict__ scales)
{
  int m = threadIdx.x;
  if (m >= C) return;
  double S1 = bn_sums[m], S2 = bn_sums[C + m], VN = bn_sums[2*C + m];
  double mu  = S1 / (double)N_NODES;
  double var = S2 / (double)N_NODES - mu*mu;
  double vn2 = VN / (3.0 * (double)N_NODES);
  scales[m]       = (float)mu;
  scales[C + m]   = gs[m] / sqrtf((float)var + EPSF);
  scales[2*C + m] = gv[m] / sqrtf((float)vn2 + EPSF);
}

// ---------------- apply BN + residual ----------------
__global__ __launch_bounds__(256) void k_apply(
    const float* __restrict__ s_new, const float* __restrict__ v_new,
    const float* __restrict__ scales, const float* __restrict__ bn_bs,
    float* __restrict__ s, float* __restrict__ v)
{
  int i = blockIdx.x * 256 + threadIdx.x;
  if (i >= N_NODES * C) return;
  int c = i & 31;
  s[i] += (s_new[i] - scales[c]) * scales[C + c] + bn_bs[c];
  float vs = scales[2*C + c];
  v[(size_t)i*3+0] += v_new[(size_t)i*3+0] * vs;
  v[(size_t)i*3+1] += v_new[(size_t)i*3+1] * vs;
  v[(size_t)i*3+2] += v_new[(size_t)i*3+2] * vs;
}

// ---------------- readout ----------------
__global__ __launch_bounds__(256) void k_readout(
    const float* __restrict__ s, const int* __restrict__ species,
    const int* __restrict__ batch,
    const float* __restrict__ W_out, const float* __restrict__ b_out,
    const float* __restrict__ atom_ref, float* __restrict__ out)
{
  __shared__ float acc[NG];
  if (threadIdx.x < NG) acc[threadIdx.x] = 0.0f;
  __syncthreads();
  int n = blockIdx.x * 256 + threadIdx.x;
  if (n < N_NODES) {
    float e = b_out[0] + atom_ref[species[n]];
    #pragma unroll
    for (int c = 0; c < C; c++) e = fmaf(s[n*C + c], W_out[c], e);
    atomicAdd(&acc[batch[n]], e);
  }
  __syncthreads();
  if (threadIdx.x < NG) {
    float a = acc[threadIdx.x];
    if (a != 0.0f) atomAddF(&out[threadIdx.x], a);
  }
}

// ================= FALLBACK (atomic path, used only if ws too small) ==========
__global__ __launch_bounds__(256) void k_edge_msg_fb(
    const float* __restrict__ basis, const float* __restrict__ Y1,
    const int* __restrict__ ei,
    const float* __restrict__ s, const float* __restrict__ v,
    const float* __restrict__ rW1, const float* __restrict__ rb1,
    const float* __restrict__ rW2, const float* __restrict__ rb2,
    const float* __restrict__ rW3, const float* __restrict__ rb3,
    float* __restrict__ agg_sf, float* __restrict__ agg_sg, float* __restrict__ agg_v)
{
  int e = blockIdx.x * 256 + threadIdx.x;
  if (e >= N_EDGES) return;
  int src = ei[e], dst = ei[N_EDGES + e];
  const float4 b0 = *(const float4*)(basis + (size_t)e*NB);
  const float4 b1 = *(const float4*)(basis + (size_t)e*NB + 4);
  float bas[NB] = {b0.x, b0.y, b0.z, b0.w, b1.x, b1.y, b1.z, b1.w};
  float h2[HID];
  #pragma unroll
  for (int j = 0; j < HID; j++) h2[j] = rb2[j];
  #pragma unroll 2
  for (int k = 0; k < HID; k++) {
    float t = rb1[k];
    #pragma unroll
    for (int b = 0; b < NB; b++) t = fmaf(bas[b], rW1[b*HID + k], t);
    float h1k = silu_f(t);
    const float* r = rW2 + k*HID;
    #pragma unroll
    for (int j = 0; j < HID; j++) h2[j] = fmaf(h1k, r[j], h2[j]);
  }
  #pragma unroll
  for (int j = 0; j < HID; j++) h2[j] = silu_f(h2[j]);
  float y0 = Y1[e*3+0], y1 = Y1[e*3+1], y2 = Y1[e*3+2];
  #pragma unroll 1
  for (int cb = 0; cb < 16; cb++) {
    float a[8];
    #pragma unroll
    for (int ci = 0; ci < 8; ci++) a[ci] = rb3[cb*8 + ci];
    #pragma unroll
    for (int k = 0; k < HID; k++) {
      float h = h2[k];
      #pragma unroll
      for (int ci = 0; ci < 8; ci++) a[ci] = fmaf(h, rW3[k*4*C + cb*8 + ci], a[ci]);
    }
    #pragma unroll
    for (int ci = 0; ci < 8; ci++) {
      int o = cb*8 + ci;
      int path = o >> 5;
      int c = o & 31;
      float xs = s[src*C + c];
      const float* vp = v + (size_t)(src*C + c)*3;
      float xv0 = vp[0], xv1 = vp[1], xv2 = vp[2];
      if (path == 0) {
        atomAddF(&agg_sf[dst*C + c], a[ci] * xs);
      } else if (path == 1) {
        atomAddF(&agg_sg[dst*C + c], a[ci] * (xv0*y0 + xv1*y1 + xv2*y2));
      } else if (path == 2) {
        float w3xs = a[ci] * xs;
        float* ap = agg_v + (size_t)(dst*C + c)*3;
        atomAddF(ap+0, w3xs*y0); atomAddF(ap+1, w3xs*y1); atomAddF(ap+2, w3xs*y2);
      } else {
        float* ap = agg_v + (size_t)(dst*C + c)*3;
        atomAddF(ap+0, a[ci]*xv0); atomAddF(ap+1, a[ci]*xv1); atomAddF(ap+2, a[ci]*xv2);
      }
    }
  }
}

__global__ __launch_bounds__(256) void k_node_update_fb(
    const float* __restrict__ agg_sf, const float* __restrict__ agg_sg,
    const float* __restrict__ agg_v,
    const float* __restrict__ Wss, const float* __restrict__ bss,
    const float* __restrict__ Wvv,
    float* __restrict__ s_new, float* __restrict__ v_new,
    double* __restrict__ bn_sums)
{
  __shared__ float lacc[3*C];
  int t = blockIdx.x * 256 + threadIdx.x;
  int n = t >> 5;
  int c = t & 31;
  if (threadIdx.x < 3*C) lacc[threadIdx.x] = 0.0f;
  __syncthreads();
  float asf = agg_sf[n*C + c];
  float asg = agg_sg[n*C + c];
  const float* ap = agg_v + (size_t)(n*C + c)*3;
  float av0 = ap[0], av1 = ap[1], av2 = ap[2];
  float sgv = silu_f(asf);
  float gate = sigmoid_f(asg);
  float vg0 = gate*av0, vg1 = gate*av1, vg2 = gate*av2;
  float sn = bss[c];
  float vm0 = 0.0f, vm1 = 0.0f, vm2 = 0.0f;
  #pragma unroll
  for (int k = 0; k < C; k++) {
    float a  = __shfl(sgv, k, 32);
    sn = fmaf(a, Wss[k*C + c], sn);
    float wv = Wvv[k*C + c];
    vm0 = fmaf(__shfl(vg0, k, 32), wv, vm0);
    vm1 = fmaf(__shfl(vg1, k, 32), wv, vm1);
    vm2 = fmaf(__shfl(vg2, k, 32), wv, vm2);
  }
  s_new[n*C + c] = sn;
  float* vo = v_new + (size_t)(n*C + c)*3;
  vo[0] = vm0; vo[1] = vm1; vo[2] = vm2;
  float vn2 = vm0*vm0 + vm1*vm1 + vm2*vm2;
  atomicAdd(&lacc[c], sn);
  atomicAdd(&lacc[C + c], sn*sn);
  atomicAdd(&lacc[2*C + c], vn2);
  __syncthreads();
  if (threadIdx.x < 3*C) atomAddD(&bn_sums[threadIdx.x], (double)lacc[threadIdx.x]);
}

extern "C" void kernel_launch(void* const* d_in, const int* in_sizes, int n_in,
                              void* d_out, int out_size, void* d_ws, size_t ws_size,
                              hipStream_t stream)
{
  const int*   species  = (const int*)  d_in[0];
  const float* pos      = (const float*)d_in[1];
  const int*   ei       = (const int*)  d_in[2];
  const int*   batch    = (const int*)  d_in[3];
  const float* emb      = (const float*)d_in[4];
  const float* freqs    = (const float*)d_in[5];
  const float* rW1      = (const float*)d_in[6];
  const float* rb1      = (const float*)d_in[7];
  const float* rW2      = (const float*)d_in[8];
  const float* rb2      = (const float*)d_in[9];
  const float* rW3      = (const float*)d_in[10];
  const float* rb3      = (const float*)d_in[11];
  const float* Wss      = (const float*)d_in[12];
  const float* bss      = (const float*)d_in[13];
  const float* Wvv      = (const float*)d_in[14];
  const float* bn_gs    = (const float*)d_in[15];
  const float* bn_bs    = (const float*)d_in[16];
  const float* bn_gv    = (const float*)d_in[17];
  const float* W_out    = (const float*)d_in[18];
  const float* b_out    = (const float*)d_in[19];
  const float* atom_ref = (const float*)d_in[20];

  float* ws = (float*)d_ws;
  size_t off = 0;
  float* basis  = ws + off; off += (size_t)N_EDGES * NB;     // fb path only
  float* Y1     = ws + off; off += (size_t)N_EDGES * 3;
  float* distb  = ws + off; off += (size_t)N_EDGES;
  float* s      = ws + off; off += (size_t)N_NODES * C;
  float* v      = ws + off; off += (size_t)N_NODES * C * 3;
  float* s_new  = ws + off; off += (size_t)N_NODES * C;
  float* v_new  = ws + off; off += (size_t)N_NODES * C * 3;
  double* bn_sums = (double*)(ws + off); off += 192;
  float* scales = ws + off; off += 96;

  // --- region A (sorted + table path) ---
  size_t ra = off;
  float* Y1s      = ws + ra;            ra += (size_t)N_EDGES * 3;
  float* dist_s   = ws + ra;            ra += (size_t)N_EDGES;
  int*   srcs     = (int*)(ws + ra);    ra += N_EDGES;
  int*   counts   = (int*)(ws + ra);    ra += N_NODES;
  int*   row_start= (int*)(ws + ra);    ra += N_NODES;
  int*   cursor   = (int*)(ws + ra);    ra += N_NODES;
  int*   bsum     = (int*)(ws + ra);    ra += 256;
  float* h2tab    = ws + ra;            ra += (size_t)NL * TBL * HID;
  float* wtab     = ws + ra;            ra += (size_t)NL * TBL * 128;
  size_t req_sorted = ra * 4;

  // --- region B (fallback atomic path, aliases region A) ---
  size_t rb = off;
  float* agg_sf = ws + rb; rb += (size_t)N_NODES * C;
  float* agg_sg = ws + rb; rb += (size_t)N_NODES * C;
  float* agg_v  = ws + rb; rb += (size_t)N_NODES * C * 3;

  dim3 b256(256);
  const int gE  = (N_EDGES + 255) / 256;
  const int gNC = (N_NODES * C + 255) / 256;
  const int gN  = (N_NODES + 255) / 256;

  hipMemsetAsync(v, 0, (size_t)N_NODES * C * 3 * sizeof(float), stream);
  k_edge_geom<<<gE, b256, 0, stream>>>(pos, ei, freqs, basis, Y1, distb);
  k_node_init<<<gNC, b256, 0, stream>>>(species, emb, s);

  if (ws_size >= req_sorted) {
    hipMemsetAsync(counts, 0, N_NODES * sizeof(int), stream);
    hipMemsetAsync(cursor, 0, N_NODES * sizeof(int), stream);
    k_hist<<<gE, b256, 0, stream>>>(ei, counts);
    k_scanA<<<NBLK_N, b256, 0, stream>>>(counts, bsum);
    k_scanB<<<1, 64, 0, stream>>>(bsum);
    k_scanC<<<NBLK_N, b256, 0, stream>>>(counts, bsum, row_start);
    k_scatter<<<gE, b256, 0, stream>>>(ei, row_start, cursor, Y1, distb,
                                       srcs, Y1s, dist_s);
    // build radial tables for both layers (8192 MLP evals total)
    k_table_h<<<(NL*TBL)/256, b256, 0, stream>>>(freqs, rW1, rb1, rW2, rb2, h2tab);
    k_table_w<<<(NL*TBL*16)/256, b256, 0, stream>>>(h2tab, rW3, rb3, wtab);

    for (int l = 0; l < NL; l++) {
      hipMemsetAsync(bn_sums, 0, 96 * sizeof(double), stream);
      k_agg_update<<<(N_NODES*C)/256, b256, 0, stream>>>(
          wtab + (size_t)l * TBL * 128, dist_s, Y1s, srcs,
          row_start, counts, s, v, Wss + l*C*C, bss + l*C, Wvv + l*C*C,
          s_new, v_new, bn_sums);
      k_bn_scales<<<1, 64, 0, stream>>>(bn_sums, bn_gs + l*C, bn_gv + l*C, scales);
      k_apply<<<gNC, b256, 0, stream>>>(s_new, v_new, scales, bn_bs + l*C, s, v);
    }
  } else {
    for (int l = 0; l < NL; l++) {
      hipMemsetAsync(agg_sf, 0, (size_t)N_NODES * 5 * C * sizeof(float), stream);
      hipMemsetAsync(bn_sums, 0, 96 * sizeof(double), stream);
      k_edge_msg_fb<<<gE, b256, 0, stream>>>(basis, Y1, ei, s, v,
          rW1 + l*NB*HID, rb1 + l*HID, rW2 + l*HID*HID, rb2 + l*HID,
          rW3 + l*HID*4*C, rb3 + l*4*C, agg_sf, agg_sg, agg_v);
      k_node_update_fb<<<(N_NODES*C)/256, b256, 0, stream>>>(agg_sf, agg_sg, agg_v,
          Wss + l*C*C, bss + l*C, Wvv + l*C*C, s_new, v_new, bn_sums);
      k_bn_scales<<<1, 64, 0, stream>>>(bn_sums, bn_gs + l*C, bn_gv + l*C, scales);
      k_apply<<<gNC, b256, 0, stream>>>(s_new, v_new, scales, bn_bs + l*C, s, v);
    }
  }

  hipMemsetAsync(d_out, 0, NG * sizeof(float), stream);
  k_readout<<<gN, b256, 0, stream>>>(s, species, batch, W_out, b_out, atom_ref, (float*)d_out);
}